// Round 1
// 176.333 us; speedup vs baseline: 1.0312x; 1.0312x over previous
//
#include <hip/hip_runtime.h>

// Problem constants
#define BATCH 32
#define CIN   256
#define CR    8
#define HDIM  56
#define WDIM  56
#define HW    3136          // 56*56 = 49*64 (waves never straddle batch rows)
#define COUT  44            // 8 z_norm + 36 interactions

// ---------------------------------------------------------------------------
// Kernel 1: 1x1 conv reduce (256 -> 8) + BatchNorm(inference) + ReLU.
// 256-thread block = 4 waves covering 64 pixels; wave w reduces cin
// [64w, 64w+64) -> 4x the wave count of the 1-thread-per-pixel version
// (6272 waves, ~24 resident waves/CU) so HBM latency is hidden by TLP.
// Loads batched 16-deep per chunk to keep >=16 vmem ops in flight per wave.
// Partials combined through an 8 KB LDS buffer; BN+ReLU fused on the way out.
// z written channels-last [pixel][8] (32B/pixel) for kernel 2.
// ---------------------------------------------------------------------------
__global__ __launch_bounds__(256) void k1_reduce_bn_relu(
    const float* __restrict__ x, const float* __restrict__ wr,
    const float* __restrict__ gamma, const float* __restrict__ beta,
    const float* __restrict__ mean, const float* __restrict__ var,
    float* __restrict__ z)
{
    const int lane = threadIdx.x & 63;
    // readfirstlane: provably wave-uniform -> weight addresses stay scalar
    const int wv   = __builtin_amdgcn_readfirstlane(threadIdx.x >> 6); // 0..3
    const int pix0 = blockIdx.x * 64;            // block's first pixel
    const int gp   = pix0 + lane;                // this thread's pixel
    const int b    = gp / HW;
    const int p    = gp - b * HW;
    const int cin0 = wv * 64;                    // this wave's cin group

    const float* __restrict__ xq =
        x + (size_t)b * CIN * HW + (size_t)cin0 * HW + p;

    float acc[CR];
#pragma unroll
    for (int c = 0; c < CR; ++c) acc[c] = 0.f;

    for (int k0 = 0; k0 < 64; k0 += 16) {
        float xv[16];
#pragma unroll
        for (int j = 0; j < 16; ++j)
            xv[j] = xq[(size_t)(k0 + j) * HW];   // coalesced 256B/wave each
#pragma unroll
        for (int j = 0; j < 16; ++j) {
            const int cin = cin0 + k0 + j;       // wave-uniform index
#pragma unroll
            for (int c = 0; c < CR; ++c)
                acc[c] = fmaf(xv[j], wr[c * CIN + cin], acc[c]);
        }
    }

    // cross-wave reduction of the 4 cin-group partials
    __shared__ float pacc[4][64][CR];            // 8 KB
#pragma unroll
    for (int c = 0; c < CR; c += 4)
        *reinterpret_cast<float4*>(&pacc[wv][lane][c]) =
            make_float4(acc[c], acc[c + 1], acc[c + 2], acc[c + 3]);
    __syncthreads();

    // 512 outputs (64 px * 8 ch), 256 threads -> 2 each; e = pix*8 + c so the
    // final store z[pix0*8 + e] is fully coalesced (1KB/wave).
    const int t = threadIdx.x;
    const int c = t & 7;                         // same c for both e's
    const float inv = gamma[c] / sqrtf(var[c] + 1e-5f);
    const float sh  = beta[c] - mean[c] * inv;
    float* zb = z + (size_t)pix0 * CR;
#pragma unroll
    for (int e = t; e < 512; e += 256) {
        const int px = e >> 3;
        const float s = pacc[0][px][c] + pacc[1][px][c]
                      + pacc[2][px][c] + pacc[3][px][c];
        zb[e] = fmaxf(fmaf(s, inv, sh), 0.f);
    }
}

// ---------------------------------------------------------------------------
// Kernel 2: depthwise 3x3 (pad 1) * scale, per-pixel L2 norms over 8 channels,
// 36 upper-triangular pairwise products, write 44 output channels (NCHW).
// Branch-free taps: every wave straddles a row boundary (56 < 64), so the old
// per-tap `if` was always divergent and serialized all 9 loads. Now: clamp the
// address (always safe), load unconditionally (all 16 loads hoist/pipeline),
// and zero the contribution via a per-lane mask on the weight.
// ---------------------------------------------------------------------------
__global__ __launch_bounds__(256) void k2_dw_norm_inter(
    const float* __restrict__ z, const float* __restrict__ wdw,
    const float* __restrict__ scale, float* __restrict__ out)
{
    const int t = blockIdx.x * 256 + threadIdx.x;   // global pixel id
    const int b = t / HW;
    const int p = t - b * HW;
    const int h = p / WDIM;
    const int w = p - h * WDIM;

    // center channels (channels-last, 32B contiguous)
    const float4 c0 = reinterpret_cast<const float4*>(z + (size_t)t * CR)[0];
    const float4 c1 = reinterpret_cast<const float4*>(z + (size_t)t * CR)[1];
    const float zc[CR] = {c0.x, c0.y, c0.z, c0.w, c1.x, c1.y, c1.z, c1.w};

    float tw[CR];
    // center tap (k=4) reuses zc, always in-bounds
#pragma unroll
    for (int c = 0; c < CR; ++c) tw[c] = zc[c] * wdw[c * 9 + 4];

    const float* __restrict__ zimg = z + (size_t)b * HW * CR;
#pragma unroll
    for (int dy = -1; dy <= 1; ++dy) {
#pragma unroll
        for (int dx = -1; dx <= 1; ++dx) {
            if (dy == 0 && dx == 0) continue;
            const int hh = h + dy, ww = w + dx;
            const bool ok = (hh >= 0) & (hh < HDIM) & (ww >= 0) & (ww < WDIM);
            const int hc = min(max(hh, 0), HDIM - 1);
            const int wc = min(max(ww, 0), WDIM - 1);
            const float m = ok ? 1.0f : 0.0f;    // per-lane mask
            const float* zn = zimg + (size_t)(hc * WDIM + wc) * CR;
            const float4 n0 = reinterpret_cast<const float4*>(zn)[0];
            const float4 n1 = reinterpret_cast<const float4*>(zn)[1];
            const float nv[CR] = {n0.x, n0.y, n0.z, n0.w, n1.x, n1.y, n1.z, n1.w};
            const int k = (dy + 1) * 3 + (dx + 1);
#pragma unroll
            for (int c = 0; c < CR; ++c)
                tw[c] = fmaf(nv[c] * m, wdw[c * 9 + k], tw[c]);
        }
    }

    float s1 = 0.f, s2 = 0.f;
#pragma unroll
    for (int c = 0; c < CR; ++c) {
        tw[c] *= scale[c];
        s1 = fmaf(zc[c], zc[c], s1);
        s2 = fmaf(tw[c], tw[c], s2);
    }
    const float r1 = 1.0f / fmaxf(sqrtf(s1), 1e-6f);
    const float r2 = 1.0f / fmaxf(sqrtf(s2), 1e-6f);

    float a[CR], tb[CR];
#pragma unroll
    for (int c = 0; c < CR; ++c) { a[c] = zc[c] * r1; tb[c] = tw[c] * r2; }

    float* op = out + (size_t)b * COUT * HW + p;
#pragma unroll
    for (int c = 0; c < CR; ++c)
        op[(size_t)c * HW] = a[c];

    int idx = CR;
#pragma unroll
    for (int i = 0; i < CR; ++i) {
#pragma unroll
        for (int j = i; j < CR; ++j) {
            op[(size_t)idx * HW] = a[i] * tb[j];
            ++idx;
        }
    }
}

extern "C" void kernel_launch(void* const* d_in, const int* in_sizes, int n_in,
                              void* d_out, int out_size, void* d_ws, size_t ws_size,
                              hipStream_t stream) {
    const float* x     = (const float*)d_in[0];
    const float* wr    = (const float*)d_in[1];
    const float* gamma = (const float*)d_in[2];
    const float* beta  = (const float*)d_in[3];
    const float* mean  = (const float*)d_in[4];
    const float* var   = (const float*)d_in[5];
    const float* wdw   = (const float*)d_in[6];
    const float* scale = (const float*)d_in[7];
    float* out = (float*)d_out;
    float* z   = (float*)d_ws;   // BATCH*HW*CR floats = 3.21 MB, channels-last

    const int npix = BATCH * HW;              // 100352
    k1_reduce_bn_relu<<<npix / 64, 256, 0, stream>>>(x, wr, gamma, beta, mean, var, z);
    k2_dw_norm_inter<<<npix / 256, 256, 0, stream>>>(z, wdw, scale, out);
}

// Round 2
// 173.198 us; speedup vs baseline: 1.0499x; 1.0181x over previous
//
#include <hip/hip_runtime.h>

// Problem constants
#define BATCH 32
#define CIN   256
#define CR    8
#define HDIM  56
#define WDIM  56
#define HW    3136          // 56*56 = 49*64 (waves never straddle batch rows)
#define COUT  44            // 8 z_norm + 36 interactions

// ---------------------------------------------------------------------------
// Kernel 1: 1x1 conv reduce (256 -> 8) + BatchNorm(inference) + ReLU.
// 256-thread block = 4 waves covering 64 pixels; wave w reduces cin
// [64w, 64w+64). Explicit 2-buffer software pipeline (xa/xb, 16 loads each):
// the next batch's 16 loads are issued BEFORE the current batch is consumed,
// so each wave always has ~16 vmem ops in flight (no vmcnt(0) drain between
// batches). Partials combined via 8 KB LDS; BN+ReLU fused on the way out.
// z written channels-last [pixel][8] (32B/pixel) for kernel 2.
// ---------------------------------------------------------------------------
__global__ __launch_bounds__(256) void k1_reduce_bn_relu(
    const float* __restrict__ x, const float* __restrict__ wr,
    const float* __restrict__ gamma, const float* __restrict__ beta,
    const float* __restrict__ mean, const float* __restrict__ var,
    float* __restrict__ z)
{
    const int lane = threadIdx.x & 63;
    // readfirstlane: provably wave-uniform -> weight addresses stay scalar
    const int wv   = __builtin_amdgcn_readfirstlane(threadIdx.x >> 6); // 0..3
    const int pix0 = blockIdx.x * 64;            // block's first pixel
    const int gp   = pix0 + lane;                // this thread's pixel
    const int b    = gp / HW;
    const int p    = gp - b * HW;
    const int cin0 = wv * 64;                    // this wave's cin group

    const float* __restrict__ xq =
        x + (size_t)b * CIN * HW + (size_t)cin0 * HW + p;

    float acc[CR];
#pragma unroll
    for (int c = 0; c < CR; ++c) acc[c] = 0.f;

    float xa[16], xb[16];
    auto loadx = [&](float (&arr)[16], int base) {
#pragma unroll
        for (int j = 0; j < 16; ++j)
            arr[j] = xq[(size_t)(base + j) * HW];   // coalesced 256B/wave each
    };
    auto consume = [&](const float (&arr)[16], int base) {
#pragma unroll
        for (int j = 0; j < 16; ++j) {
            const int cin = cin0 + base + j;        // wave-uniform index
#pragma unroll
            for (int c = 0; c < CR; ++c)
                acc[c] = fmaf(arr[j], wr[c * CIN + cin], acc[c]);
        }
    };

    loadx(xa, 0);
    loadx(xb, 16);          // in flight while xa is consumed
    consume(xa, 0);
    loadx(xa, 32);          // in flight while xb is consumed
    consume(xb, 16);
    loadx(xb, 48);          // in flight while xa is consumed
    consume(xa, 32);
    consume(xb, 48);

    // cross-wave reduction of the 4 cin-group partials
    __shared__ float pacc[4][64][CR];            // 8 KB
#pragma unroll
    for (int c = 0; c < CR; c += 4)
        *reinterpret_cast<float4*>(&pacc[wv][lane][c]) =
            make_float4(acc[c], acc[c + 1], acc[c + 2], acc[c + 3]);
    __syncthreads();

    // 512 outputs (64 px * 8 ch), 256 threads -> 2 each; e = pix*8 + c so the
    // final store z[pix0*8 + e] is fully coalesced (1KB/wave).
    const int t = threadIdx.x;
    const int c = t & 7;                         // same c for both e's
    const float inv = gamma[c] / sqrtf(var[c] + 1e-5f);
    const float sh  = beta[c] - mean[c] * inv;
    float* zb = z + (size_t)pix0 * CR;
#pragma unroll
    for (int e = t; e < 512; e += 256) {
        const int px = e >> 3;
        const float s = pacc[0][px][c] + pacc[1][px][c]
                      + pacc[2][px][c] + pacc[3][px][c];
        zb[e] = fmaxf(fmaf(s, inv, sh), 0.f);
    }
}

// ---------------------------------------------------------------------------
// Kernel 2: depthwise 3x3 (pad 1) * scale, per-pixel L2 norms over 8 channels,
// 36 upper-triangular pairwise products, write 44 output channels (NCHW).
// All 9 taps (18 float4 loads) are issued into registers BEFORE any FMA: one
// waitcnt for 18 in-flight loads instead of per-tap serialization. Tap 4 (the
// center) doubles as zc, saving the duplicate center load. Out-of-bounds taps
// use clamped (always-safe) addresses and are zeroed via a per-lane mask.
// 64-thread blocks: 1568 blocks spread ~6/CU for latency hiding.
// ---------------------------------------------------------------------------
__global__ __launch_bounds__(64) void k2_dw_norm_inter(
    const float* __restrict__ z, const float* __restrict__ wdw,
    const float* __restrict__ scale, float* __restrict__ out)
{
    const int t = blockIdx.x * 64 + threadIdx.x;   // global pixel id
    const int b = t / HW;
    const int p = t - b * HW;
    const int h = p / WDIM;
    const int w = p - h * WDIM;
    const float* __restrict__ zimg = z + (size_t)b * HW * CR;

    // ---- issue all 9 tap loads first (fully unrolled -> static reg indices)
    float4 n0[9], n1[9];
    float  mk[9];
#pragma unroll
    for (int dy = -1; dy <= 1; ++dy) {
#pragma unroll
        for (int dx = -1; dx <= 1; ++dx) {
            const int k  = (dy + 1) * 3 + (dx + 1);
            const int hh = h + dy, ww = w + dx;
            const bool ok = (hh >= 0) & (hh < HDIM) & (ww >= 0) & (ww < WDIM);
            const int hc = min(max(hh, 0), HDIM - 1);
            const int wc = min(max(ww, 0), WDIM - 1);
            mk[k] = ok ? 1.0f : 0.0f;            // per-lane mask (tap4 -> 1)
            const float* zn = zimg + (size_t)(hc * WDIM + wc) * CR;
            n0[k] = reinterpret_cast<const float4*>(zn)[0];
            n1[k] = reinterpret_cast<const float4*>(zn)[1];
        }
    }

    // center channels = tap 4 (always in-bounds)
    const float zc[CR] = {n0[4].x, n0[4].y, n0[4].z, n0[4].w,
                          n1[4].x, n1[4].y, n1[4].z, n1[4].w};

    // ---- depthwise 3x3
    float tw[CR];
#pragma unroll
    for (int c = 0; c < CR; ++c) tw[c] = 0.f;
#pragma unroll
    for (int k = 0; k < 9; ++k) {
        const float nv[CR] = {n0[k].x, n0[k].y, n0[k].z, n0[k].w,
                              n1[k].x, n1[k].y, n1[k].z, n1[k].w};
#pragma unroll
        for (int c = 0; c < CR; ++c)
            tw[c] = fmaf(nv[c] * mk[k], wdw[c * 9 + k], tw[c]);
    }

    // ---- norms
    float s1 = 0.f, s2 = 0.f;
#pragma unroll
    for (int c = 0; c < CR; ++c) {
        tw[c] *= scale[c];
        s1 = fmaf(zc[c], zc[c], s1);
        s2 = fmaf(tw[c], tw[c], s2);
    }
    const float r1 = 1.0f / fmaxf(sqrtf(s1), 1e-6f);
    const float r2 = 1.0f / fmaxf(sqrtf(s2), 1e-6f);

    float a[CR], tb[CR];
#pragma unroll
    for (int c = 0; c < CR; ++c) { a[c] = zc[c] * r1; tb[c] = tw[c] * r2; }

    // ---- 44 output channels (NCHW), 256B/wave coalesced per channel
    float* op = out + (size_t)b * COUT * HW + p;
#pragma unroll
    for (int c = 0; c < CR; ++c)
        op[(size_t)c * HW] = a[c];

    int idx = CR;
#pragma unroll
    for (int i = 0; i < CR; ++i) {
#pragma unroll
        for (int j = i; j < CR; ++j) {
            op[(size_t)idx * HW] = a[i] * tb[j];
            ++idx;
        }
    }
}

extern "C" void kernel_launch(void* const* d_in, const int* in_sizes, int n_in,
                              void* d_out, int out_size, void* d_ws, size_t ws_size,
                              hipStream_t stream) {
    const float* x     = (const float*)d_in[0];
    const float* wr    = (const float*)d_in[1];
    const float* gamma = (const float*)d_in[2];
    const float* beta  = (const float*)d_in[3];
    const float* mean  = (const float*)d_in[4];
    const float* var   = (const float*)d_in[5];
    const float* wdw   = (const float*)d_in[6];
    const float* scale = (const float*)d_in[7];
    float* out = (float*)d_out;
    float* z   = (float*)d_ws;   // BATCH*HW*CR floats = 3.21 MB, channels-last

    const int npix = BATCH * HW;              // 100352
    k1_reduce_bn_relu<<<npix / 64, 256, 0, stream>>>(x, wr, gamma, beta, mean, var, z);
    k2_dw_norm_inter<<<npix / 64, 64, 0, stream>>>(z, wdw, scale, out);
}